// Round 9
// baseline (139.512 us; speedup 1.0000x reference)
//
#include <hip/hip_runtime.h>
#include <hip/hip_fp16.h>

// GEMM view: Out[(b,d), c] = sum_k A[(b,d),k] * Bk[k,c]
//   row = b*32 + d (M=131072), k = i*32+j (K=1024), col = c (N=64)
// A[(b,d), i*32+j] = x[b,i,d] * y[b,j,d]  — rank-1 in (i,j), built in regs.
// R9: occupancy fix. Grid 1024, block = 4 b's; wave = 4 M-tiles x 2 N-tiles
// (N-split; A-gen is cheap f16 now). LDS 48 KB (xs 16 + kb 2x16) ->
// 3 blocks/CU = 12 waves/CU (was 8). acc 32 VGPR.
// DIAGNOSTIC rep=3 retained for counter visibility; strip next round.

typedef __attribute__((ext_vector_type(8))) _Float16 half8;   // MFMA operand
typedef __attribute__((ext_vector_type(2))) __fp16 fp16x2;    // cvt_pkrtz/pk_mul
typedef __attribute__((ext_vector_type(4))) float f32x4;
typedef __attribute__((ext_vector_type(8))) short short8;

__device__ __forceinline__ unsigned int dup_h(float f) {
    union { fp16x2 h; unsigned int u; } w;
    w.h = __builtin_amdgcn_cvt_pkrtz(f, f);
    return w.u;
}
__device__ __forceinline__ fp16x2 pk2(float a, float b) {
    return __builtin_amdgcn_cvt_pkrtz(a, b);
}

// kswz f16 frag order: g = (s*4+nt)*64 + lane,
// kswz[g*8+t] = f16(kernel[c = nt*16+(lane&15)][s][(lane>>4)*8 + t])
__global__ __launch_bounds__(256) void kswz_kernel(const float* __restrict__ kern,
                                                   unsigned short* __restrict__ kswz) {
    int idx  = blockIdx.x * 256 + threadIdx.x;  // 8192
    int lane = idx & 63;
    int nt   = (idx >> 6) & 3;
    int s    = idx >> 8;
    int c    = nt * 16 + (lane & 15);
    int jb   = (lane >> 4) * 8;
    const float* src = kern + c * 1024 + s * 32 + jb;
    union { half8 h; short8 s8; } v;
#pragma unroll
    for (int t = 0; t < 8; ++t) v.h[t] = (_Float16)src[t];  // RNE
    *(short8*)(kswz + (size_t)idx * 8) = v.s8;
}

__device__ __forceinline__ void gld_lds16(const void* g, void* l) {
    __builtin_amdgcn_global_load_lds(
        (const __attribute__((address_space(1))) unsigned int*)g,
        (__attribute__((address_space(3))) unsigned int*)l, 16, 0, 0);
}

__global__ __launch_bounds__(256, 4) void cin_main(const float* __restrict__ x,
                                                   const float* __restrict__ y,
                                                   const unsigned short* __restrict__ kswz,
                                                   float* __restrict__ out_mat,
                                                   float* __restrict__ out_fin) {
    __shared__ unsigned int xs[4 * 1024];                 // 16 KB dup'd f16 x (4 b's)
    __shared__ __align__(16) unsigned short kb[2][8192];  // 2 x 16 KB B chunks

    const int tid  = threadIdx.x;
    const int wave = tid >> 6;        // 0..3
    const int lane = tid & 63;
    const int quad = lane >> 4;
    const int n16  = lane & 15;
    const int bpair = wave >> 1;      // which 2 b's
    const int nth   = wave & 1;       // which half of C
    const int b_blk = blockIdx.x * 4;
    const int cq0   = blockIdx.x & 7;
    const int b0    = b_blk + bpair * 2;

    for (int rep = 0; rep < 3; ++rep) {   // DIAGNOSTIC x3 (idempotent)
        __syncthreads();  // protect xs/kb from previous rep's readers

        // ---- DMA first kswz chunk (16 KB) ----
#pragma unroll
        for (int r = 0; r < 4; ++r)
            gld_lds16(kswz + (size_t)cq0 * 8192 + (r * 256 + tid) * 8,
                      &kb[0][r * 2048 + wave * 512]);

        // ---- stage x (4 b's) as dup'd f16 pairs: xs[b_loc*1024 + i*32 + d] ----
        {
            const float4* xg4 = (const float4*)(x + (size_t)b_blk * 1024);
#pragma unroll
            for (int r = 0; r < 4; ++r) {
                int i4 = r * 256 + tid;   // 1024 float4 per block
                float4 v = xg4[i4];
                uint4 w;
                w.x = dup_h(v.x); w.y = dup_h(v.y); w.z = dup_h(v.z); w.w = dup_h(v.w);
                *(uint4*)&xs[i4 * 4] = w;
            }
        }

        // ---- y fragments as packed f16 pairs ----
        fp16x2 yv2[4][4];
#pragma unroll
        for (int mt = 0; mt < 4; ++mt) {
            const int b = b0 + (mt >> 1);
            const int d = n16 + 16 * (mt & 1);
            const float* yp = y + (size_t)b * 1024 + (quad * 8) * 32 + d;
#pragma unroll
            for (int p = 0; p < 4; ++p)
                yv2[mt][p] = pk2(yp[(2 * p) * 32], yp[(2 * p + 1) * 32]);
        }

        f32x4 acc[4][2];
#pragma unroll
        for (int mt = 0; mt < 4; ++mt)
#pragma unroll
            for (int ntl = 0; ntl < 2; ++ntl) acc[mt][ntl] = (f32x4){0.f, 0.f, 0.f, 0.f};

        int xoff[4];
#pragma unroll
        for (int mt = 0; mt < 4; ++mt)
            xoff[mt] = (bpair * 2 + (mt >> 1)) * 1024 + n16 + 16 * (mt & 1);

        __syncthreads();

        for (int p8 = 0; p8 < 8; ++p8) {
            if (p8 < 7) {
                const int cn = (cq0 + p8 + 1) & 7;
                unsigned short* dst = &kb[(p8 + 1) & 1][0];
#pragma unroll
                for (int r = 0; r < 4; ++r)
                    gld_lds16(kswz + (size_t)cn * 8192 + (r * 256 + tid) * 8,
                              dst + r * 2048 + wave * 512);
            }

            const unsigned short* kbase = &kb[p8 & 1][0];
            const int sb = ((cq0 + p8) & 7) * 4;
#pragma unroll
            for (int k = 0; k < 4; ++k) {
                // wave's two N-tiles: nt = 2*nth, 2*nth+1
                const half8 bf0 = *(const half8*)(kbase + (k * 4 + nth * 2) * 512 + lane * 8);
                const half8 bf1 = *(const half8*)(kbase + (k * 4 + nth * 2 + 1) * 512 + lane * 8);
#pragma unroll
                for (int mt = 0; mt < 4; ++mt) {
                    union { unsigned int u; fp16x2 h; } xv;
                    xv.u = xs[xoff[mt] + (sb + k) * 32];
                    union { half8 h8; fp16x2 h2[4]; } af;
#pragma unroll
                    for (int p = 0; p < 4; ++p) af.h2[p] = xv.h * yv2[mt][p];  // v_pk_mul_f16
                    acc[mt][0] = __builtin_amdgcn_mfma_f32_16x16x32_f16(af.h8, bf0, acc[mt][0], 0, 0, 0);
                    acc[mt][1] = __builtin_amdgcn_mfma_f32_16x16x32_f16(af.h8, bf1, acc[mt][1], 0, 0, 0);
                }
            }
            __syncthreads();
        }

        // ---- epilogue: output_mat[b][c][d], d = 16*(mt&1) + quad*4 + t ----
#pragma unroll
        for (int mt = 0; mt < 4; ++mt) {
            const int b = b0 + (mt >> 1);
            const int dbase = 16 * (mt & 1) + quad * 4;
#pragma unroll
            for (int ntl = 0; ntl < 2; ++ntl) {
                const int c = (nth * 2 + ntl) * 16 + n16;
                *(f32x4*)(out_mat + (size_t)b * 2048 + c * 32 + dbase) = acc[mt][ntl];
            }
        }

        // ---- final_output[b][c] = sum_d output_mat[b][c][d] ----
#pragma unroll
        for (int a = 0; a < 2; ++a) {
            const int b = b0 + a;
#pragma unroll
            for (int ntl = 0; ntl < 2; ++ntl) {
                float f = 0.f;
#pragma unroll
                for (int t = 0; t < 4; ++t) f += acc[2 * a][ntl][t] + acc[2 * a + 1][ntl][t];
                f += __shfl_xor(f, 16);
                f += __shfl_xor(f, 32);
                if (lane < 16) out_fin[(size_t)b * 64 + (nth * 2 + ntl) * 16 + n16] = f;
            }
        }
    }
}

extern "C" void kernel_launch(void* const* d_in, const int* in_sizes, int n_in,
                              void* d_out, int out_size, void* d_ws, size_t ws_size,
                              hipStream_t stream) {
    const float* x    = (const float*)d_in[0];   // [4096,32,32]
    const float* y    = (const float*)d_in[1];   // [4096,32,32]
    const float* kern = (const float*)d_in[2];   // [64,32,32]
    float* out_mat = (float*)d_out;                      // [4096,64,32]
    float* out_fin = (float*)d_out + 4096 * 64 * 32;     // [4096,64]
    unsigned short* kswz = (unsigned short*)d_ws;        // 65536 f16 = 128 KB

    kswz_kernel<<<32, 256, 0, stream>>>(kern, kswz);
    cin_main<<<1024, 256, 0, stream>>>(x, y, kswz, out_mat, out_fin);
}

// Round 10
// 130.527 us; speedup vs baseline: 1.0688x; 1.0688x over previous
//
#include <hip/hip_runtime.h>
#include <hip/hip_fp16.h>

// GEMM view: Out[(b,d), c] = sum_k A[(b,d),k] * Bk[k,c]
//   row = b*32 + d (M=131072), k = i*32+j (K=1024), col = c (N=64)
// A[(b,d), i*32+j] = x[b,i,d] * y[b,j,d]  — rank-1 in (i,j), built in regs.
// R10 = R8 skeleton (full-C 2-b waves, grid 512, kb dbuf) +
//  (1) xs as non-dup f16 transposed [b][d][i], row-pad 36: per chunk per mt
//      ONE ds_read_b64 gives 4 steps' x; dup via v_perm_b32.
//  (2) explicit B-frag register prefetch (k+1 during k).
// DIAGNOSTIC rep=3 retained; strip next round.

typedef __attribute__((ext_vector_type(8))) _Float16 half8;   // MFMA operand
typedef __attribute__((ext_vector_type(2))) __fp16 fp16x2;    // cvt_pkrtz/pk_mul
typedef __attribute__((ext_vector_type(4))) float f32x4;
typedef __attribute__((ext_vector_type(8))) short short8;

__device__ __forceinline__ fp16x2 pk2(float a, float b) {
    return __builtin_amdgcn_cvt_pkrtz(a, b);
}
__device__ __forceinline__ fp16x2 dup_lo(unsigned int r) {
    union { unsigned int u; fp16x2 h; } w;
    w.u = __builtin_amdgcn_perm(0u, r, 0x01000100u);  // {lo16, lo16}
    return w.h;
}
__device__ __forceinline__ fp16x2 dup_hi(unsigned int r) {
    union { unsigned int u; fp16x2 h; } w;
    w.u = __builtin_amdgcn_perm(0u, r, 0x03020302u);  // {hi16, hi16}
    return w.h;
}

// kswz f16 frag order: g = (s*4+nt)*64 + lane,
// kswz[g*8+t] = f16(kernel[c = nt*16+(lane&15)][s][(lane>>4)*8 + t])
__global__ __launch_bounds__(256) void kswz_kernel(const float* __restrict__ kern,
                                                   unsigned short* __restrict__ kswz) {
    int idx  = blockIdx.x * 256 + threadIdx.x;  // 8192
    int lane = idx & 63;
    int nt   = (idx >> 6) & 3;
    int s    = idx >> 8;
    int c    = nt * 16 + (lane & 15);
    int jb   = (lane >> 4) * 8;
    const float* src = kern + c * 1024 + s * 32 + jb;
    union { half8 h; short8 s8; } v;
#pragma unroll
    for (int t = 0; t < 8; ++t) v.h[t] = (_Float16)src[t];  // RNE
    *(short8*)(kswz + (size_t)idx * 8) = v.s8;
}

__device__ __forceinline__ void gld_lds16(const void* g, void* l) {
    __builtin_amdgcn_global_load_lds(
        (const __attribute__((address_space(1))) unsigned int*)g,
        (__attribute__((address_space(3))) unsigned int*)l, 16, 0, 0);
}

#define XROW 36  // padded i-row length (u16) — 72 B rows, 8 B-aligned, bank-spread

__global__ __launch_bounds__(256, 2) void cin_main(const float* __restrict__ x,
                                                   const float* __restrict__ y,
                                                   const unsigned short* __restrict__ kswz,
                                                   float* __restrict__ out_mat,
                                                   float* __restrict__ out_fin) {
    __shared__ unsigned short xs16[8 * 32 * XROW];        // 18 KB f16 x, [b][d][i] pad-36
    __shared__ __align__(16) unsigned short kb[2][8192];  // 2 x 16 KB B chunks

    const int tid  = threadIdx.x;
    const int wave = tid >> 6;        // 0..3
    const int lane = tid & 63;
    const int quad = lane >> 4;
    const int n16  = lane & 15;
    const int b_blk = blockIdx.x * 8;
    const int cq0   = blockIdx.x & 7;
    const int bpair = wave;           // wave owns b0 = b_blk + wave*2 .. +1
    const int b0    = b_blk + bpair * 2;

    for (int rep = 0; rep < 3; ++rep) {   // DIAGNOSTIC x3 (idempotent)
        __syncthreads();  // protect xs/kb from previous rep's readers

        // ---- DMA first kswz chunk (16 KB) ----
#pragma unroll
        for (int r = 0; r < 4; ++r)
            gld_lds16(kswz + (size_t)cq0 * 8192 + (r * 256 + tid) * 8,
                      &kb[0][r * 2048 + wave * 512]);

        // ---- stage x transposed: xs16[(b_loc*32 + d)*XROW + i] = f16(x[b][i][d]) ----
        {
            const float4* xg4 = (const float4*)(x + (size_t)b_blk * 1024);
#pragma unroll
            for (int r = 0; r < 8; ++r) {
                int i4 = r * 256 + tid;           // 2048 float4 total
                int bl = i4 >> 8;                 // b_loc
                int ii = (i4 >> 3) & 31;          // i
                int dd = (i4 & 7) * 4;            // d base
                float4 v = xg4[i4];
                unsigned short* p = &xs16[(bl * 32 + dd) * XROW + ii];
                union { __fp16 h; unsigned short u; } c0, c1, c2, c3;
                c0.h = (__fp16)v.x; c1.h = (__fp16)v.y;
                c2.h = (__fp16)v.z; c3.h = (__fp16)v.w;
                p[0 * XROW] = c0.u; p[1 * XROW] = c1.u;
                p[2 * XROW] = c2.u; p[3 * XROW] = c3.u;
            }
        }

        // ---- y fragments as packed pairs ----
        fp16x2 yv2[4][4];
#pragma unroll
        for (int mt = 0; mt < 4; ++mt) {
            const int b = b0 + (mt >> 1);
            const int d = n16 + 16 * (mt & 1);
            const float* yp = y + (size_t)b * 1024 + (quad * 8) * 32 + d;
#pragma unroll
            for (int p = 0; p < 4; ++p)
                yv2[mt][p] = pk2(yp[(2 * p) * 32], yp[(2 * p + 1) * 32]);
        }

        f32x4 acc[4][4];
#pragma unroll
        for (int mt = 0; mt < 4; ++mt)
#pragma unroll
            for (int nt = 0; nt < 4; ++nt) acc[mt][nt] = (f32x4){0.f, 0.f, 0.f, 0.f};

        // per-mt x row offset (u16 units) into xs16
        int xrow[4];
#pragma unroll
        for (int mt = 0; mt < 4; ++mt)
            xrow[mt] = ((bpair * 2 + (mt >> 1)) * 32 + n16 + 16 * (mt & 1)) * XROW;

        __syncthreads();

        for (int p8 = 0; p8 < 8; ++p8) {
            if (p8 < 7) {
                const int cn = (cq0 + p8 + 1) & 7;
                unsigned short* dst = &kb[(p8 + 1) & 1][0];
#pragma unroll
                for (int r = 0; r < 4; ++r)
                    gld_lds16(kswz + (size_t)cn * 8192 + (r * 256 + tid) * 8,
                              dst + r * 2048 + wave * 512);
            }

            const unsigned short* kbase = &kb[p8 & 1][0];
            const int sb = ((cq0 + p8) & 7) * 4;

            // x for all 4 steps of this chunk: 1 ds_read_b64 + 4 v_perm per mt
            fp16x2 xdu[4][4];
#pragma unroll
            for (int mt = 0; mt < 4; ++mt) {
                const uint2 xr = *(const uint2*)(xs16 + xrow[mt] + sb);
                xdu[mt][0] = dup_lo(xr.x); xdu[mt][1] = dup_hi(xr.x);
                xdu[mt][2] = dup_lo(xr.y); xdu[mt][3] = dup_hi(xr.y);
            }

            // B-frag prefetch: bfc = step k, bfn = step k+1
            half8 bfc[4], bfn[4];
#pragma unroll
            for (int nt = 0; nt < 4; ++nt)
                bfc[nt] = *(const half8*)(kbase + nt * 512 + lane * 8);

#pragma unroll
            for (int k = 0; k < 4; ++k) {
                if (k < 3) {
#pragma unroll
                    for (int nt = 0; nt < 4; ++nt)
                        bfn[nt] = *(const half8*)(kbase + ((k + 1) * 4 + nt) * 512 + lane * 8);
                }
#pragma unroll
                for (int mt = 0; mt < 4; ++mt) {
                    union { half8 h8; fp16x2 h2[4]; } af;
#pragma unroll
                    for (int p = 0; p < 4; ++p) af.h2[p] = xdu[mt][k] * yv2[mt][p];
#pragma unroll
                    for (int nt = 0; nt < 4; ++nt)
                        acc[mt][nt] = __builtin_amdgcn_mfma_f32_16x16x32_f16(
                            af.h8, bfc[nt], acc[mt][nt], 0, 0, 0);
                }
#pragma unroll
                for (int nt = 0; nt < 4; ++nt) bfc[nt] = bfn[nt];
            }
            __syncthreads();
        }

        // ---- epilogue: output_mat[b][c][d], d = 16*(mt&1) + quad*4 + t ----
#pragma unroll
        for (int mt = 0; mt < 4; ++mt) {
            const int b = b0 + (mt >> 1);
            const int dbase = 16 * (mt & 1) + quad * 4;
#pragma unroll
            for (int nt = 0; nt < 4; ++nt) {
                const int c = nt * 16 + n16;
                *(f32x4*)(out_mat + (size_t)b * 2048 + c * 32 + dbase) = acc[mt][nt];
            }
        }

        // ---- final_output[b][c] = sum_d output_mat[b][c][d] ----
#pragma unroll
        for (int a = 0; a < 2; ++a) {
            const int b = b0 + a;
#pragma unroll
            for (int nt = 0; nt < 4; ++nt) {
                float f = 0.f;
#pragma unroll
                for (int t = 0; t < 4; ++t) f += acc[2 * a][nt][t] + acc[2 * a + 1][nt][t];
                f += __shfl_xor(f, 16);
                f += __shfl_xor(f, 32);
                if (lane < 16) out_fin[(size_t)b * 64 + nt * 16 + n16] = f;
            }
        }
    }
}

extern "C" void kernel_launch(void* const* d_in, const int* in_sizes, int n_in,
                              void* d_out, int out_size, void* d_ws, size_t ws_size,
                              hipStream_t stream) {
    const float* x    = (const float*)d_in[0];   // [4096,32,32]
    const float* y    = (const float*)d_in[1];   // [4096,32,32]
    const float* kern = (const float*)d_in[2];   // [64,32,32]
    float* out_mat = (float*)d_out;                      // [4096,64,32]
    float* out_fin = (float*)d_out + 4096 * 64 * 32;     // [4096,64]
    unsigned short* kswz = (unsigned short*)d_ws;        // 65536 f16 = 128 KB

    kswz_kernel<<<32, 256, 0, stream>>>(kern, kswz);
    cin_main<<<512, 256, 0, stream>>>(x, y, kswz, out_mat, out_fin);
}